// Round 4
// baseline (302.027 us; speedup 1.0000x reference)
//
#include <hip/hip_runtime.h>
#include <hip/hip_bf16.h>
#include <stdint.h>

// Problem constants: NA=NT=1024, A_DIM=E_DIM=128, L=128, K = L*128 = 16384

typedef short bf16x8 __attribute__((ext_vector_type(8)));
typedef float f32x4  __attribute__((ext_vector_type(4)));

#define GLD16(g, l) __builtin_amdgcn_global_load_lds( \
    (const __attribute__((address_space(1))) void*)(uintptr_t)(g), \
    (__attribute__((address_space(3))) void*)(uintptr_t)(l), 16, 0, 0)

// ---------------- prep: transpose inputs [1024][1024] -> inputsT ----------------
__global__ __launch_bounds__(256) void transpose_int_kernel(const int* __restrict__ in,
                                                            int* __restrict__ out) {
    __shared__ int tile[32][33];
    int b = blockIdx.x;              // 1024 tiles
    int tr = b >> 5, tc = b & 31;
    int r0 = tr * 32, c0 = tc * 32;
    int tx = threadIdx.x & 31, ty = threadIdx.x >> 5;
#pragma unroll
    for (int p = 0; p < 4; ++p)
        tile[ty + p * 8][tx] = in[(size_t)(r0 + ty + p * 8) * 1024 + c0 + tx];
    __syncthreads();
#pragma unroll
    for (int p = 0; p < 4; ++p) {
        int cc = ty + p * 8;
        out[(size_t)(c0 + cc) * 1024 + r0 + tx] = tile[tx][cc];
    }
}

// ------------- prep: transpose+cast weights f32 [16384][128] -> bf16 [128][16384] -------------
__global__ __launch_bounds__(256) void transpose_w_kernel(const float* __restrict__ W0,
                                                          const float* __restrict__ W1,
                                                          uint16_t* __restrict__ O0,
                                                          uint16_t* __restrict__ O1) {
    __shared__ float tile[32][33];
    int b = blockIdx.x;              // 4096 tiles (2048 per weight)
    const float* W = W0;
    uint16_t* O = O0;
    if (b >= 2048) { b -= 2048; W = W1; O = O1; }
    int tr = b >> 2, tc = b & 3;
    int r0 = tr * 32, c0 = tc * 32;
    int tx = threadIdx.x & 31, ty = threadIdx.x >> 5;
#pragma unroll
    for (int p = 0; p < 4; ++p)
        tile[ty + p * 8][tx] = W[(size_t)(r0 + ty + p * 8) * 128 + c0 + tx];
    __syncthreads();
#pragma unroll
    for (int p = 0; p < 4; ++p) {
        int cc = ty + p * 8;
        __hip_bfloat16 h = __float2bfloat16(tile[tx][cc]);
        O[(size_t)(c0 + cc) * 16384 + r0 + tx] = *(uint16_t*)&h;
    }
}

// ---------------- prep: CSR build — parallel deterministic counting sort ----------------
__global__ __launch_bounds__(128) void csr_build_kernel(const int* __restrict__ inA,
                                                        const int* __restrict__ inT,
                                                        uint16_t* __restrict__ idxA,
                                                        uint16_t* __restrict__ idxT,
                                                        int* __restrict__ offA,
                                                        int* __restrict__ offT) {
    __shared__ uint16_t chist[128][128];  // 32 KiB [chunk][label]
    __shared__ int lab[1024];
    __shared__ int tot[128];
    __shared__ int off[128];
    int b = blockIdx.x;
    const int* in = inA; uint16_t* idx = idxA; int* offo = offA; int row = b;
    if (b >= 1024) { in = inT; idx = idxT; offo = offT; row = b - 1024; }
    const int c = threadIdx.x;            // 0..127

    for (int i = c; i < 8192; i += 128) ((uint32_t*)chist)[i] = 0;
    for (int i = c; i < 1024; i += 128) lab[i] = in[(size_t)row * 1024 + i];
    __syncthreads();

    int mylab[8], rloc[8];
#pragma unroll
    for (int k = 0; k < 8; ++k) {
        int l = lab[c * 8 + k];
        mylab[k] = l;
        rloc[k] = chist[c][l];
        chist[c][l] = (uint16_t)(rloc[k] + 1);
    }
    __syncthreads();

    {   // column prefix over chunks: thread c owns label l=c
        int run = 0;
#pragma unroll 4
        for (int ch = 0; ch < 128; ++ch) {
            int v = chist[ch][c];
            chist[ch][c] = (uint16_t)run;
            run += v;
        }
        tot[c] = run;
    }
    __syncthreads();
    if (c == 0) {
        int s = 0;
#pragma unroll 4
        for (int l = 0; l < 128; ++l) { off[l] = s; s += tot[l]; }
    }
    __syncthreads();
    offo[(size_t)row * 128 + c] = off[c];
#pragma unroll
    for (int k = 0; k < 8; ++k) {
        int l = mylab[k];
        int pos = off[l] + (int)chist[c][l] + rloc[k];
        idx[(size_t)row * 1024 + pos] = (uint16_t)(c * 8 + k);
    }
}

// ---------------- prep: init output + bf16 mirrors ----------------
__global__ __launch_bounds__(256) void init_out_kernel(const float* __restrict__ fa,
                                                       const float* __restrict__ ft,
                                                       float* __restrict__ out,
                                                       uint16_t* __restrict__ srcAb,
                                                       uint16_t* __restrict__ srcTb) {
    int i = blockIdx.x * 256 + threadIdx.x;   // grid 2048 -> 524288
    int r = i >> 8, c = i & 255;
    float v = 0.f;
    if (c < 128) {
        v = (r < 1024) ? fa[(size_t)r * 128 + c] : ft[(size_t)(r - 1024) * 128 + c];
        __hip_bfloat16 h = __float2bfloat16(v);
        if (r < 1024) srcAb[(size_t)r * 128 + c] = *(uint16_t*)&h;
        else          srcTb[(size_t)(r - 1024) * 128 + c] = *(uint16_t*)&h;
    }
    out[i] = v;
}

// ---------------- mirror: state f32 (stride 256) -> bf16 (stride 128) ----------------
__global__ __launch_bounds__(256) void mirror_kernel(const float* __restrict__ state,
                                                     uint32_t* __restrict__ dst32) {
    int i = blockIdx.x * 256 + threadIdx.x;   // grid 256 -> 65536 threads, 2 floats each
    int idx2 = i * 2;
    int r = idx2 >> 7, c = idx2 & 127;
    float2 v = *(const float2*)(state + (size_t)r * 256 + c);
    __hip_bfloat16 h0 = __float2bfloat16(v.x), h1 = __float2bfloat16(v.y);
    dst32[i] = ((uint32_t)(*(uint16_t*)&h1) << 16) | (uint32_t)(*(uint16_t*)&h0);
}

// ---------------- bucket via CSR (bf16 src): U[j, l*128+e] = sum_{t in list(j,l)} src[t][e] ----------------
// 1 block per j, 8 waves, 16 labels per wave, lane covers 2 e-channels (one u32 read/row).
__global__ __launch_bounds__(512) void bucket_csr_kernel(const uint16_t* __restrict__ idx,
                                                         const int* __restrict__ off,
                                                         const uint32_t* __restrict__ srcb, // [1024][64] u32
                                                         uint32_t* __restrict__ U32) {      // [1024][8192]
    __shared__ uint16_t sidx[1024];
    __shared__ int soff[129];
    const int j = blockIdx.x;
    const int tid = threadIdx.x;
    const int wv = tid >> 6, lane = tid & 63;

    if (tid < 512) {
        ((uint32_t*)sidx)[tid] = ((const uint32_t*)(idx + (size_t)j * 1024))[tid];
    }
    if (tid < 128) soff[tid] = off[(size_t)j * 128 + tid];
    if (tid == 0) soff[128] = 1024;
    __syncthreads();

#pragma unroll 1
    for (int li = 0; li < 16; ++li) {
        int l = wv * 16 + li;
        int s = soff[l];
        int e = soff[l + 1];
        float a0 = 0.f, a1 = 0.f, b0 = 0.f, b1 = 0.f;
        int p = s;
        for (; p + 3 < e; p += 4) {
            uint32_t v0 = srcb[(size_t)sidx[p] * 64 + lane];
            uint32_t v1 = srcb[(size_t)sidx[p + 1] * 64 + lane];
            uint32_t v2 = srcb[(size_t)sidx[p + 2] * 64 + lane];
            uint32_t v3 = srcb[(size_t)sidx[p + 3] * 64 + lane];
            a0 += __uint_as_float(v0 << 16) + __uint_as_float(v1 << 16);
            a1 += __uint_as_float(v0 & 0xffff0000u) + __uint_as_float(v1 & 0xffff0000u);
            b0 += __uint_as_float(v2 << 16) + __uint_as_float(v3 << 16);
            b1 += __uint_as_float(v2 & 0xffff0000u) + __uint_as_float(v3 & 0xffff0000u);
        }
        for (; p < e; ++p) {
            uint32_t v0 = srcb[(size_t)sidx[p] * 64 + lane];
            a0 += __uint_as_float(v0 << 16);
            a1 += __uint_as_float(v0 & 0xffff0000u);
        }
        float r0 = a0 + b0, r1 = a1 + b1;
        __hip_bfloat16 h0 = __float2bfloat16(r0), h1 = __float2bfloat16(r1);
        uint32_t pk = ((uint32_t)(*(uint16_t*)&h1) << 16) | (uint32_t)(*(uint16_t*)&h0);
        U32[(size_t)j * 8192 + l * 64 + lane] = pk;
    }
}

// ---------------- GEMM: state[1024][*256] += A[1024][16384] x Bt[128][16384]^T ----------------
// grid (8 m-tiles, 64 k-chunks) = 512 blocks (2/CU), 256 thr = 4 waves (2x2),
// 64x64 per wave, 16x16x32 bf16 MFMA, K=256 per block (4 x BK=64).
__global__ __launch_bounds__(256) void gemm_kernel(const uint16_t* __restrict__ A,
                                                   const uint16_t* __restrict__ Bt,
                                                   float* __restrict__ outacc) {
    __shared__ uint16_t Atile[128 * 64];   // 16 KiB, XOR-swizzled 16B slots
    __shared__ uint16_t Btile[128 * 64];

    const int tid = threadIdx.x;
    const int lane = tid & 63;
    const int wid = tid >> 6;
    const int wr = wid >> 1, wc = wid & 1;
    const int mbase = blockIdx.x * 128;
    const size_t kchunk = (size_t)blockIdx.y * 256;

    f32x4 acc[4][4] = {};

    const int rlane = lane >> 3;
    const int slane = lane & 7;

    for (int it = 0; it < 4; ++it) {
        const size_t kb2 = (kchunk + (size_t)it * 64) * 2;
#pragma unroll
        for (int c = 0; c < 4; ++c) {
            int r = c * 32 + wid * 8 + rlane;
            int col16 = slane ^ (r & 7);                     // pre-swizzled source (involution)
            const char* gA = (const char*)A + (size_t)(mbase + r) * 32768 + kb2 + col16 * 16;
            char* lA = (char*)Atile + c * 4096 + wid * 1024; // wave-uniform linear dest
            GLD16(gA, lA);
            const char* gB = (const char*)Bt + (size_t)r * 32768 + kb2 + col16 * 16;
            char* lB = (char*)Btile + c * 4096 + wid * 1024;
            GLD16(gB, lB);
        }
        __syncthreads();

#pragma unroll
        for (int kk = 0; kk < 2; ++kk) {
            bf16x8 af[4], bfr[4];
            const int q = lane >> 4;
            const int rl = lane & 15;
#pragma unroll
            for (int m = 0; m < 4; ++m) {
                int row = wr * 64 + m * 16 + rl;
                int sw = (kk * 4 + q) ^ (row & 7);
                af[m] = *(const bf16x8*)((const char*)Atile + row * 128 + sw * 16);
            }
#pragma unroll
            for (int n = 0; n < 4; ++n) {
                int row = wc * 64 + n * 16 + rl;
                int sw = (kk * 4 + q) ^ (row & 7);
                bfr[n] = *(const bf16x8*)((const char*)Btile + row * 128 + sw * 16);
            }
#pragma unroll
            for (int m = 0; m < 4; ++m)
#pragma unroll
                for (int n = 0; n < 4; ++n)
                    acc[m][n] = __builtin_amdgcn_mfma_f32_16x16x32_bf16(af[m], bfr[n], acc[m][n], 0, 0, 0);
        }
        __syncthreads();
    }

    const int rq = lane >> 4;   // C/D: col=lane&15, row=(lane>>4)*4+reg
    const int cn = lane & 15;
#pragma unroll
    for (int m = 0; m < 4; ++m)
#pragma unroll
        for (int n = 0; n < 4; ++n)
#pragma unroll
            for (int r = 0; r < 4; ++r) {
                int row = mbase + wr * 64 + m * 16 + rq * 4 + r;
                int col = wc * 64 + n * 16 + cn;
                unsafeAtomicAdd(&outacc[(size_t)row * 256 + col], acc[m][n][r]);
            }
}

extern "C" void kernel_launch(void* const* d_in, const int* in_sizes, int n_in,
                              void* d_out, int out_size, void* d_ws, size_t ws_size,
                              hipStream_t stream) {
    const int*   inputs  = (const int*)d_in[0];
    const float* first_a = (const float*)d_in[1];
    const float* first_t = (const float*)d_in[2];
    const float* Awij    = (const float*)d_in[3];
    const float* Awij2   = (const float*)d_in[4];
    float* out = (float*)d_out;

    // workspace layout (46 MiB total)
    char* w = (char*)d_ws;
    uint16_t* U       = (uint16_t*)(w);                 // 32 MiB  [1024][16384] bf16
    int*      inputsT = (int*)(w);                      // 4 MiB, prep-only, aliases U
    uint16_t* BtA     = (uint16_t*)(w + (32u << 20));   // 4 MiB  [a][l*128+e] = Awij2[l][e][a]
    uint16_t* BtT     = (uint16_t*)(w + (36u << 20));   // 4 MiB  [e][l*128+a] = Awij[l][a][e]
    uint16_t* idxA    = (uint16_t*)(w + (40u << 20));   // 2 MiB
    uint16_t* idxT    = (uint16_t*)(w + (42u << 20));   // 2 MiB
    int*      offA    = (int*)(w + (44u << 20));        // 512 KiB
    int*      offT    = (int*)(w + (44u << 20) + (1u << 19)); // 512 KiB
    uint16_t* srcAb   = (uint16_t*)(w + (45u << 20));   // 256 KiB bf16 mirror of stateA
    uint16_t* srcTb   = (uint16_t*)(w + (45u << 20) + (1u << 18)); // 256 KiB mirror of stateT
    if (ws_size < (46u << 20)) return;

    float* stateA = out;                 // [1024][256], cols 0..127 live
    float* stateT = out + 1024 * 256;    // [1024][256], cols 0..127 live

    transpose_int_kernel<<<1024, 256, 0, stream>>>(inputs, inputsT);
    transpose_w_kernel<<<4096, 256, 0, stream>>>(Awij2, Awij, BtA, BtT);
    csr_build_kernel<<<2048, 128, 0, stream>>>(inputs, inputsT, idxA, idxT, offA, offT);
    init_out_kernel<<<2048, 256, 0, stream>>>(first_a, first_t, out, srcAb, srcTb);

    for (int s = 0; s < 2; ++s) {
        // Phase A: a += bucket_t(update_t) x Awij2
        bucket_csr_kernel<<<1024, 512, 0, stream>>>(idxA, offA, (const uint32_t*)srcTb, (uint32_t*)U);
        gemm_kernel<<<dim3(8, 64), 256, 0, stream>>>(U, BtA, stateA);
        mirror_kernel<<<256, 256, 0, stream>>>(stateA, (uint32_t*)srcAb);
        // Phase T: t += bucket_j(new_a) x Awij
        bucket_csr_kernel<<<1024, 512, 0, stream>>>(idxT, offT, (const uint32_t*)srcAb, (uint32_t*)U);
        gemm_kernel<<<dim3(8, 64), 256, 0, stream>>>(U, BtT, stateT);
        if (s == 0)
            mirror_kernel<<<256, 256, 0, stream>>>(stateT, (uint32_t*)srcTb);
    }
}